// Round 14
// baseline (157.445 us; speedup 1.0000x reference)
//
#include <hip/hip_runtime.h>

typedef __attribute__((ext_vector_type(8))) short short8;
typedef __attribute__((ext_vector_type(4))) float floatx4;
typedef __attribute__((ext_vector_type(16))) float floatx16;
typedef __attribute__((ext_vector_type(4))) float f32x4;

#define BS   32768

__device__ __forceinline__ unsigned short f2bf(float f) {
  unsigned int u = __float_as_uint(f);
  u += 0x7fffu + ((u >> 16) & 1u);   // round-to-nearest-even
  return (unsigned short)(u >> 16);
}

// merged prep: blocks 0..511 transpose We -> WeT bf16; blocks 512..527 Wg -> WgT
__global__ void prep_w(const float* __restrict__ We, const float* __restrict__ Wg,
                       unsigned short* __restrict__ WeT, unsigned short* __restrict__ WgT) {
  int bid = blockIdx.x;
  if (bid < 512) {
    int e  = bid >> 6;
    int kc = bid & 63;
    int h  = threadIdx.x;
    short8 pk;
#pragma unroll
    for (int j = 0; j < 8; ++j)
      pk[j] = (short)f2bf(We[e * 131072 + (kc * 8 + j) * 256 + h]);
    *reinterpret_cast<short8*>(&WeT[e * 131072 + h * 512 + kc * 8]) = pk;
  } else if (threadIdx.x < 64) {
    int row = bid - 512;              // 16 rows: t*8+e
    int t = row >> 3, e = row & 7;
    int lane = threadIdx.x;
    short8 pk;
#pragma unroll
    for (int j = 0; j < 8; ++j)
      pk[j] = (short)f2bf(Wg[t * 4096 + (lane * 8 + j) * 8 + e]);
    *reinterpret_cast<short8*>(&WgT[row * 512 + lane * 8]) = pk;
  }
}

#define GLOAD16(SRC, DST) \
  __builtin_amdgcn_global_load_lds( \
      (const __attribute__((address_space(1))) unsigned int*)(SRC), \
      (__attribute__((address_space(3))) unsigned int*)(DST), 16, 0, 0)

// kernel2: convert xv -> Abf (bf16, pre-swizzled 32KB chunks [mt][kc][256r][64k])
// and compute gates -> gates_ws[16][32768] (col-major planes, col = t*8+e).
__global__ __launch_bounds__(256) void conv_gates(
    const float* __restrict__ xv, const unsigned short* __restrict__ WgT,
    const float* __restrict__ bg, unsigned short* __restrict__ Abf,
    float* __restrict__ gates_ws)
{
  __shared__ __attribute__((aligned(16))) unsigned char bufA[65536]; // 64r x 1024B, swizzled
  const int tid = threadIdx.x;
  const int b0  = blockIdx.x * 64;
  const int r8 = tid >> 3, kslot = tid & 7;
  const int mt = b0 >> 8;
  const int rc_base = b0 & 255;
  unsigned char* AbfB = reinterpret_cast<unsigned char*>(Abf);

#pragma unroll
  for (int pass = 0; pass < 2; ++pass) {
    int r = pass * 32 + r8;
    int r_c = rc_base + r;
    const float* xrow = xv + (size_t)(b0 + r) * 512;
    unsigned swz = (unsigned)((r & 7) << 4);
#pragma unroll
    for (int j = 0; j < 8; ++j) {
      int o = j * 8 + kslot;
      f32x4 v0 = *reinterpret_cast<const f32x4*>(xrow + o * 8);
      f32x4 v1 = *reinterpret_cast<const f32x4*>(xrow + o * 8 + 4);
      short8 pk;
      pk[0] = (short)f2bf(v0[0]); pk[1] = (short)f2bf(v0[1]);
      pk[2] = (short)f2bf(v0[2]); pk[3] = (short)f2bf(v0[3]);
      pk[4] = (short)f2bf(v1[0]); pk[5] = (short)f2bf(v1[1]);
      pk[6] = (short)f2bf(v1[2]); pk[7] = (short)f2bf(v1[3]);
      unsigned lb = ((unsigned)r << 10) + (((unsigned)(o * 16)) ^ swz);
      *reinterpret_cast<short8*>(&bufA[lb]) = pk;
      unsigned gb = (unsigned)((mt * 8 + j) * 32768) + (unsigned)(r_c * 128)
                  + (((unsigned)(kslot * 16)) ^ swz);
      *reinterpret_cast<short8*>(&AbfB[gb]) = pk;
    }
  }
  __syncthreads();

  const int wave = tid >> 6, lane = tid & 63;
  const int row16 = lane & 15, kgrp = lane >> 4;
  floatx4 gacc = {0.f, 0.f, 0.f, 0.f};
  const unsigned abase = ((unsigned)row16 << 10) + ((unsigned)kgrp << 4) + ((unsigned)wave << 14);
  const unsigned a_swz = (unsigned)((row16 & 7) << 4);
  const unsigned short* wg_lane = WgT + row16 * 512 + kgrp * 8;
#pragma unroll
  for (int ks = 0; ks < 16; ++ks) {
    short8 af = *reinterpret_cast<const short8*>(&bufA[(abase + (unsigned)(ks << 6)) ^ a_swz]);
    short8 bf = *reinterpret_cast<const short8*>(wg_lane + ks * 32);
    gacc = __builtin_amdgcn_mfma_f32_16x16x32_bf16(af, bf, gacc, 0, 0, 0);
  }
  float bgv = bg[row16];
#pragma unroll
  for (int j = 0; j < 4; ++j) {
    float v = gacc[j] + bgv;
    float mx = v;
    mx = fmaxf(mx, __shfl_xor(mx, 1));
    mx = fmaxf(mx, __shfl_xor(mx, 2));
    mx = fmaxf(mx, __shfl_xor(mx, 4));
    float p = __expf(v - mx);
    float s = p;
    s += __shfl_xor(s, 1);
    s += __shfl_xor(s, 2);
    s += __shfl_xor(s, 4);
    gates_ws[row16 * BS + b0 + wave * 16 + kgrp * 4 + j] = p / s;
  }
}

// main v14: v13 structure (XCD-locality e=bid>>7, unified kt-top staging,
// counted vmcnt(8)) but inner loop on mfma_f32_32x32x16_bf16: wave tile
// 128x64 = 4 mfrag x 2 nfrag of 32x32 (acc 8 x floatx16 = 128 AGPR);
// per kstep(16k): 6 ds_read_b128 -> lgkm(6)-pipelined -> 8 MFMA.
__global__ __launch_bounds__(512, 2) void mmoe_main(
    const unsigned short* __restrict__ Abf,   // [128 mt][8 kc][16384], pre-swizzled
    const unsigned short* __restrict__ WeT,   // [8][256][512]
    const float* __restrict__ gates_ws,       // [16][32768]
    const float* __restrict__ be,             // [8][256]
    const float* __restrict__ Wt,             // [2][256]
    float* __restrict__ acc_ws)               // [2][32768]
{
  __shared__ __attribute__((aligned(16))) unsigned char smem[131072]; // A0|A1|B0|B1
  __shared__ float red_lds[4][256][2];

  const int tid = threadIdx.x, wave = tid >> 6, lane = tid & 63;
  const int l31 = lane & 31, lh = lane >> 5;   // 32x32 frag: row/col = l31, k-half = lh
  const int wm = wave >> 2, wn = wave & 3;
  const int bid = blockIdx.x;
  const int e = bid >> 7, mt = bid & 127;      // XCD-locality mapping

  const unsigned short* Asrc = Abf + (size_t)mt * 131072;
  const unsigned short* Bsrc = WeT + e * 131072;

  unsigned soffB[4];
#pragma unroll
  for (int i = 0; i < 4; ++i) {
    unsigned x = (unsigned)(i * 8192 + tid * 16);
    unsigned r = x >> 7;
    unsigned y = (x & 127u) ^ ((r & 7u) << 4);
    soffB[i] = r * 512u + (y >> 1);
  }
  const unsigned soffA0 = (unsigned)(tid * 8);

  unsigned char* Ab0 = smem;
  unsigned char* Ab1 = smem + 32768;
  unsigned char* Bb0 = smem + 65536;
  unsigned char* Bb1 = smem + 98304;

  // prologue: stage kt0
#pragma unroll
  for (int i = 0; i < 4; ++i)
    GLOAD16(Asrc + (i * 4096 + soffA0), Ab0 + (i * 8 + wave) * 1024);
#pragma unroll
  for (int i = 0; i < 4; ++i)
    GLOAD16(Bsrc + soffB[i], Bb0 + (i * 8 + wave) * 1024);

  floatx16 acc[4][2];
#pragma unroll
  for (int mf = 0; mf < 4; ++mf)
#pragma unroll
    for (int nf = 0; nf < 2; ++nf)
#pragma unroll
      for (int q = 0; q < 16; ++q) acc[mf][nf][q] = 0.f;

  // read address components (32x32 frags)
  const unsigned arow = (unsigned)(wm * 128);          // + mf*32 + l31
  const unsigned bcol = (unsigned)(wn * 64);           // + nf*32 + l31
  const unsigned koff0 = (unsigned)(lh * 16);          // + ks*32, XOR (row&7)<<4

  // RD: one 16B frag read. ROWIDX = arow/bcol + F*32 + l31 ; swz key = (l31&7)
#define RDF(BUF, ROWBASE, F, KS) \
  (*reinterpret_cast<const short8*>( \
      &(BUF)[((ROWBASE) + (unsigned)((F) * 32) + (unsigned)l31) * 128 + \
             (((unsigned)((KS) * 32) + koff0) ^ (unsigned)((l31 & 7) << 4))]))

#define RD6(AB, BB, KS, AV, BV) \
  AV[0] = RDF(AB, arow, 0, KS); AV[1] = RDF(AB, arow, 1, KS); \
  AV[2] = RDF(AB, arow, 2, KS); AV[3] = RDF(AB, arow, 3, KS); \
  BV[0] = RDF(BB, bcol, 0, KS); BV[1] = RDF(BB, bcol, 1, KS);

#define MFMA8(AV, BV) \
  _Pragma("unroll") \
  for (int mf = 0; mf < 4; ++mf) { \
    acc[mf][0] = __builtin_amdgcn_mfma_f32_32x32x16_bf16(AV[mf], BV[0], acc[mf][0], 0, 0, 0); \
    acc[mf][1] = __builtin_amdgcn_mfma_f32_32x32x16_bf16(AV[mf], BV[1], acc[mf][1], 0, 0, 0); \
  }

#pragma unroll
  for (int kt = 0; kt < 8; ++kt) {
    const unsigned char* ab = (kt & 1) ? Ab1 : Ab0;
    const unsigned char* bb = (kt & 1) ? Bb1 : Bb0;
    unsigned char* an = (kt & 1) ? Ab0 : Ab1;
    unsigned char* bn = (kt & 1) ? Bb0 : Bb1;
    const unsigned short* aNext = Asrc + (kt + 1) * 16384;
    const unsigned short* bNext = Bsrc + (kt + 1) * 64;

    // kt top: stage A(kt+1)+B(kt+1); counted vmcnt(8)
    if (kt < 7) {
#pragma unroll
      for (int i = 0; i < 4; ++i)
        GLOAD16(aNext + (i * 4096 + soffA0), an + (i * 8 + wave) * 1024);
#pragma unroll
      for (int i = 0; i < 4; ++i)
        GLOAD16(bNext + soffB[i], bn + (i * 8 + wave) * 1024);
      asm volatile("s_waitcnt vmcnt(8)" ::: "memory");
    } else {
      asm volatile("s_waitcnt vmcnt(0)" ::: "memory");
    }
    __builtin_amdgcn_s_barrier();
    __builtin_amdgcn_sched_barrier(0);

    short8 av0[4], bv0[2], av1[4], bv1[2], av2[4], bv2[2], av3[4], bv3[2];
    RD6(ab, bb, 0, av0, bv0);
    RD6(ab, bb, 1, av1, bv1);
    asm volatile("s_waitcnt lgkmcnt(6)" ::: "memory");   // ks0 ready; ks1 in flight
    __builtin_amdgcn_sched_barrier(0);
    __builtin_amdgcn_s_setprio(1);
    MFMA8(av0, bv0);
    __builtin_amdgcn_s_setprio(0);
    RD6(ab, bb, 2, av2, bv2);
    asm volatile("s_waitcnt lgkmcnt(6)" ::: "memory");   // ks1 ready; ks2 in flight
    __builtin_amdgcn_sched_barrier(0);
    __builtin_amdgcn_s_setprio(1);
    MFMA8(av1, bv1);
    __builtin_amdgcn_s_setprio(0);
    RD6(ab, bb, 3, av3, bv3);
    asm volatile("s_waitcnt lgkmcnt(6)" ::: "memory");   // ks2 ready; ks3 in flight
    __builtin_amdgcn_sched_barrier(0);
    __builtin_amdgcn_s_setprio(1);
    MFMA8(av2, bv2);
    __builtin_amdgcn_s_setprio(0);
    asm volatile("s_waitcnt lgkmcnt(0)" ::: "memory");
    __builtin_amdgcn_sched_barrier(0);
    __builtin_amdgcn_s_setprio(1);
    MFMA8(av3, bv3);
    __builtin_amdgcn_s_setprio(0);
    __builtin_amdgcn_s_barrier();                        // reads of kt's bufs done
    __builtin_amdgcn_sched_barrier(0);
  }
#undef RDF
#undef RD6
#undef MFMA8

  // ---- epilogue: 32x32 C/D layout col=lane&31, row=(reg&3)+8*(reg>>2)+4*lh ----
  float bev[2], wt0[2], wt1[2];
#pragma unroll
  for (int nf = 0; nf < 2; ++nf) {
    int h = wn * 64 + nf * 32 + l31;
    bev[nf] = be[e * 256 + h];
    wt0[nf] = Wt[h];
    wt1[nf] = Wt[256 + h];
  }

#pragma unroll
  for (int mf = 0; mf < 4; ++mf) {
#pragma unroll
    for (int q = 0; q < 16; ++q) {
      float s0 = 0.f, s1 = 0.f;
#pragma unroll
      for (int nf = 0; nf < 2; ++nf) {
        float r = fmaxf(acc[mf][nf][q] + bev[nf], 0.f);
        s0 = fmaf(r, wt0[nf], s0);
        s1 = fmaf(r, wt1[nf], s1);
      }
      s0 += __shfl_xor(s0, 1);  s1 += __shfl_xor(s1, 1);
      s0 += __shfl_xor(s0, 2);  s1 += __shfl_xor(s1, 2);
      s0 += __shfl_xor(s0, 4);  s1 += __shfl_xor(s1, 4);
      s0 += __shfl_xor(s0, 8);  s1 += __shfl_xor(s1, 8);
      s0 += __shfl_xor(s0, 16); s1 += __shfl_xor(s1, 16);
      if (l31 == 0) {
        int rl = (q & 3) + 8 * (q >> 2) + 4 * lh;
        int row = wm * 128 + mf * 32 + rl;
        red_lds[wn][row][0] = s0;
        red_lds[wn][row][1] = s1;
      }
    }
  }
  __syncthreads();

  {
    int row = tid >> 1, t = tid & 1;
    float s = red_lds[0][row][t] + red_lds[1][row][t]
            + red_lds[2][row][t] + red_lds[3][row][t];
    float g = gates_ws[(t * 8 + e) * BS + mt * 256 + row];
    atomicAdd(&acc_ws[t * BS + mt * 256 + row], s * g);
  }
}

__global__ void finalize(const float* __restrict__ acc_ws, const float* __restrict__ bt,
                         float* __restrict__ out) {
  int i = blockIdx.x * 256 + threadIdx.x;   // 65536
  int t = i >> 15;
  float s = fmaxf(acc_ws[i] + bt[t], 0.f);
  out[i] = 1.f / (1.f + __expf(-s));
}

extern "C" void kernel_launch(void* const* d_in, const int* in_sizes, int n_in,
                              void* d_out, int out_size, void* d_ws, size_t ws_size,
                              hipStream_t stream) {
  const float* xv = (const float*)d_in[0];
  const float* We = (const float*)d_in[1];
  const float* be = (const float*)d_in[2];
  const float* Wg = (const float*)d_in[3];
  const float* bg = (const float*)d_in[4];
  const float* Wt = (const float*)d_in[5];
  const float* bt = (const float*)d_in[6];
  float* out = (float*)d_out;

  unsigned char* ws = (unsigned char*)d_ws;
  unsigned short* WeT      = (unsigned short*)(ws);                     // 2 MiB
  unsigned short* WgT      = (unsigned short*)(ws + (2u << 20));        // 16 KiB
  unsigned short* Abf      = (unsigned short*)(ws + (4u << 20));        // 32 MiB
  float*          gates_ws = (float*)(ws + (36u << 20));                // 2 MiB
  float*          acc_ws   = (float*)(ws + (38u << 20));                // 256 KiB

  hipMemsetAsync(acc_ws, 0, 2 * BS * sizeof(float), stream);
  prep_w<<<528, 256, 0, stream>>>(We, Wg, WeT, WgT);
  conv_gates<<<512, 256, 0, stream>>>(xv, WgT, bg, Abf, gates_ws);
  mmoe_main<<<1024, 512, 0, stream>>>(Abf, WeT, gates_ws, be, Wt, acc_ws);
  finalize<<<256, 256, 0, stream>>>(acc_ws, bt, out);
}

// Round 15
// 122.630 us; speedup vs baseline: 1.2839x; 1.2839x over previous
//
#include <hip/hip_runtime.h>

typedef __attribute__((ext_vector_type(8))) short short8;
typedef __attribute__((ext_vector_type(4))) float floatx4;
typedef __attribute__((ext_vector_type(4))) float f32x4;

#define BS   32768

__device__ __forceinline__ unsigned short f2bf(float f) {
  unsigned int u = __float_as_uint(f);
  u += 0x7fffu + ((u >> 16) & 1u);   // round-to-nearest-even
  return (unsigned short)(u >> 16);
}

// merged prep: blocks 0..511 transpose We -> WeT bf16; blocks 512..527 Wg -> WgT
__global__ void prep_w(const float* __restrict__ We, const float* __restrict__ Wg,
                       unsigned short* __restrict__ WeT, unsigned short* __restrict__ WgT) {
  int bid = blockIdx.x;
  if (bid < 512) {
    int e  = bid >> 6;
    int kc = bid & 63;
    int h  = threadIdx.x;
    short8 pk;
#pragma unroll
    for (int j = 0; j < 8; ++j)
      pk[j] = (short)f2bf(We[e * 131072 + (kc * 8 + j) * 256 + h]);
    *reinterpret_cast<short8*>(&WeT[e * 131072 + h * 512 + kc * 8]) = pk;
  } else if (threadIdx.x < 64) {
    int row = bid - 512;              // 16 rows: t*8+e
    int t = row >> 3, e = row & 7;
    int lane = threadIdx.x;
    short8 pk;
#pragma unroll
    for (int j = 0; j < 8; ++j)
      pk[j] = (short)f2bf(Wg[t * 4096 + (lane * 8 + j) * 8 + e]);
    *reinterpret_cast<short8*>(&WgT[row * 512 + lane * 8]) = pk;
  }
}

#define GLOAD16(SRC, DST) \
  __builtin_amdgcn_global_load_lds( \
      (const __attribute__((address_space(1))) unsigned int*)(SRC), \
      (__attribute__((address_space(3))) unsigned int*)(DST), 16, 0, 0)

// kernel2: convert xv -> Abf (bf16, pre-swizzled 32KB chunks [mt][kc][256r][64k])
// and compute gates -> gates_ws[16][32768] (col-major planes, col = t*8+e).
__global__ __launch_bounds__(256) void conv_gates(
    const float* __restrict__ xv, const unsigned short* __restrict__ WgT,
    const float* __restrict__ bg, unsigned short* __restrict__ Abf,
    float* __restrict__ gates_ws)
{
  __shared__ __attribute__((aligned(16))) unsigned char bufA[65536]; // 64r x 1024B, swizzled
  const int tid = threadIdx.x;
  const int b0  = blockIdx.x * 64;
  const int r8 = tid >> 3, kslot = tid & 7;
  const int mt = b0 >> 8;
  const int rc_base = b0 & 255;
  unsigned char* AbfB = reinterpret_cast<unsigned char*>(Abf);

#pragma unroll
  for (int pass = 0; pass < 2; ++pass) {
    int r = pass * 32 + r8;
    int r_c = rc_base + r;
    const float* xrow = xv + (size_t)(b0 + r) * 512;
    unsigned swz = (unsigned)((r & 7) << 4);
#pragma unroll
    for (int j = 0; j < 8; ++j) {
      int o = j * 8 + kslot;
      f32x4 v0 = *reinterpret_cast<const f32x4*>(xrow + o * 8);
      f32x4 v1 = *reinterpret_cast<const f32x4*>(xrow + o * 8 + 4);
      short8 pk;
      pk[0] = (short)f2bf(v0[0]); pk[1] = (short)f2bf(v0[1]);
      pk[2] = (short)f2bf(v0[2]); pk[3] = (short)f2bf(v0[3]);
      pk[4] = (short)f2bf(v1[0]); pk[5] = (short)f2bf(v1[1]);
      pk[6] = (short)f2bf(v1[2]); pk[7] = (short)f2bf(v1[3]);
      unsigned lb = ((unsigned)r << 10) + (((unsigned)(o * 16)) ^ swz);
      *reinterpret_cast<short8*>(&bufA[lb]) = pk;
      unsigned gb = (unsigned)((mt * 8 + j) * 32768) + (unsigned)(r_c * 128)
                  + (((unsigned)(kslot * 16)) ^ swz);
      *reinterpret_cast<short8*>(&AbfB[gb]) = pk;
    }
  }
  __syncthreads();

  const int wave = tid >> 6, lane = tid & 63;
  const int row16 = lane & 15, kgrp = lane >> 4;
  floatx4 gacc = {0.f, 0.f, 0.f, 0.f};
  const unsigned abase = ((unsigned)row16 << 10) + ((unsigned)kgrp << 4) + ((unsigned)wave << 14);
  const unsigned a_swz = (unsigned)((row16 & 7) << 4);
  const unsigned short* wg_lane = WgT + row16 * 512 + kgrp * 8;
#pragma unroll
  for (int ks = 0; ks < 16; ++ks) {
    short8 af = *reinterpret_cast<const short8*>(&bufA[(abase + (unsigned)(ks << 6)) ^ a_swz]);
    short8 bf = *reinterpret_cast<const short8*>(wg_lane + ks * 32);
    gacc = __builtin_amdgcn_mfma_f32_16x16x32_bf16(af, bf, gacc, 0, 0, 0);
  }
  float bgv = bg[row16];
#pragma unroll
  for (int j = 0; j < 4; ++j) {
    float v = gacc[j] + bgv;
    float mx = v;
    mx = fmaxf(mx, __shfl_xor(mx, 1));
    mx = fmaxf(mx, __shfl_xor(mx, 2));
    mx = fmaxf(mx, __shfl_xor(mx, 4));
    float p = __expf(v - mx);
    float s = p;
    s += __shfl_xor(s, 1);
    s += __shfl_xor(s, 2);
    s += __shfl_xor(s, 4);
    gates_ws[row16 * BS + b0 + wave * 16 + kgrp * 4 + j] = p / s;
  }
}

// main v15: v13 data layout (16x16 MFMA, XCD-locality e=bid>>7) + faithful m201
// phase template: per kt 4 phases x {ds_read subtile BEFORE barrier -> stage
// (ph0) -> barrier -> lgkmcnt(0) -> setprio(1) 16 MFMA setprio(0) -> barrier};
// vmcnt(0) at ph3 (3 phases after stage issue -> free).
__global__ __launch_bounds__(512, 2) void mmoe_main(
    const unsigned short* __restrict__ Abf,   // [128 mt][8 kc][16384], pre-swizzled
    const unsigned short* __restrict__ WeT,   // [8][256][512]
    const float* __restrict__ gates_ws,       // [16][32768]
    const float* __restrict__ be,             // [8][256]
    const float* __restrict__ Wt,             // [2][256]
    float* __restrict__ acc_ws)               // [2][32768]
{
  __shared__ __attribute__((aligned(16))) unsigned char smem[131072]; // A0|A1|B0|B1
  __shared__ float red_lds[4][256][2];

  const int tid = threadIdx.x, wave = tid >> 6, lane = tid & 63;
  const int row16 = lane & 15, kgrp = lane >> 4;
  const int wm = wave >> 2, wn = wave & 3;
  const int bid = blockIdx.x;
  const int e = bid >> 7, mt = bid & 127;     // XCD-locality mapping

  const unsigned short* Asrc = Abf + (size_t)mt * 131072;
  const unsigned short* Bsrc = WeT + e * 131072;

  unsigned soffB[4];
#pragma unroll
  for (int i = 0; i < 4; ++i) {
    unsigned x = (unsigned)(i * 8192 + tid * 16);
    unsigned r = x >> 7;
    unsigned y = (x & 127u) ^ ((r & 7u) << 4);
    soffB[i] = r * 512u + (y >> 1);
  }
  const unsigned soffA0 = (unsigned)(tid * 8);

  unsigned char* Ab0 = smem;
  unsigned char* Ab1 = smem + 32768;
  unsigned char* Bb0 = smem + 65536;
  unsigned char* Bb1 = smem + 98304;

  // prologue: stage kt0, full drain
#pragma unroll
  for (int i = 0; i < 4; ++i)
    GLOAD16(Asrc + (i * 4096 + soffA0), Ab0 + (i * 8 + wave) * 1024);
#pragma unroll
  for (int i = 0; i < 4; ++i)
    GLOAD16(Bsrc + soffB[i], Bb0 + (i * 8 + wave) * 1024);
  asm volatile("s_waitcnt vmcnt(0)" ::: "memory");
  __syncthreads();

  floatx4 acc[8][4];
#pragma unroll
  for (int mf = 0; mf < 8; ++mf)
#pragma unroll
    for (int n = 0; n < 4; ++n) acc[mf][n] = (floatx4){0.f, 0.f, 0.f, 0.f};

  const unsigned swz  = (unsigned)((row16 & 7) << 4);
  const unsigned bcol = (unsigned)(wn * 64 + row16);
  const unsigned arow = (unsigned)(wm * 128 + row16);

#define RDA(AB, MF, KS) \
  (*reinterpret_cast<const short8*>( \
      &(AB)[(arow + (unsigned)((MF) * 16)) * 128 + (((unsigned)((KS) * 64 + kgrp * 16)) ^ swz)]))

#define MFMA4(ACC, AV, BV) \
  _Pragma("unroll") \
  for (int n = 0; n < 4; ++n) \
    ACC[n] = __builtin_amdgcn_mfma_f32_16x16x32_bf16(AV, BV[n], ACC[n], 0, 0, 0);

#pragma unroll
  for (int kt = 0; kt < 8; ++kt) {
    const unsigned char* ab = (kt & 1) ? Ab1 : Ab0;
    const unsigned char* bb = (kt & 1) ? Bb1 : Bb0;
    unsigned char* an = (kt & 1) ? Ab0 : Ab1;
    unsigned char* bn = (kt & 1) ? Bb0 : Bb1;
    const unsigned short* aNext = Asrc + (kt + 1) * 16384;
    const unsigned short* bNext = Bsrc + (kt + 1) * 64;

    // ======== ph0: reads(bf x8 + mf0,1 x4) | stage kt+1 | bar | 16 MFMA | bar ====
    short8 bf[2][4];
#pragma unroll
    for (int ks = 0; ks < 2; ++ks)
#pragma unroll
      for (int n = 0; n < 4; ++n)
        bf[ks][n] = *reinterpret_cast<const short8*>(
            &bb[(bcol + (unsigned)(n * 16)) * 128 + (((unsigned)(ks * 64 + kgrp * 16)) ^ swz)]);
    short8 a00 = RDA(ab, 0, 0), a01 = RDA(ab, 0, 1);
    short8 a10 = RDA(ab, 1, 0), a11 = RDA(ab, 1, 1);
    if (kt < 7) {
#pragma unroll
      for (int i = 0; i < 4; ++i)
        GLOAD16(aNext + (i * 4096 + soffA0), an + (i * 8 + wave) * 1024);
#pragma unroll
      for (int i = 0; i < 4; ++i)
        GLOAD16(bNext + soffB[i], bn + (i * 8 + wave) * 1024);
    }
    asm volatile("s_waitcnt lgkmcnt(8)" ::: "memory");   // 12 issued; partial drain
    __builtin_amdgcn_s_barrier();
    asm volatile("s_waitcnt lgkmcnt(0)" ::: "memory");
    __builtin_amdgcn_sched_barrier(0);
    __builtin_amdgcn_s_setprio(1);
    MFMA4(acc[0], a00, bf[0]); MFMA4(acc[0], a01, bf[1]);
    MFMA4(acc[1], a10, bf[0]); MFMA4(acc[1], a11, bf[1]);
    __builtin_amdgcn_s_setprio(0);
    __builtin_amdgcn_s_barrier();

    // ======== ph1: reads mf2,3 | bar | 16 MFMA | bar ========
    short8 b00 = RDA(ab, 2, 0), b01 = RDA(ab, 2, 1);
    short8 b10 = RDA(ab, 3, 0), b11 = RDA(ab, 3, 1);
    __builtin_amdgcn_s_barrier();
    asm volatile("s_waitcnt lgkmcnt(0)" ::: "memory");
    __builtin_amdgcn_sched_barrier(0);
    __builtin_amdgcn_s_setprio(1);
    MFMA4(acc[2], b00, bf[0]); MFMA4(acc[2], b01, bf[1]);
    MFMA4(acc[3], b10, bf[0]); MFMA4(acc[3], b11, bf[1]);
    __builtin_amdgcn_s_setprio(0);
    __builtin_amdgcn_s_barrier();

    // ======== ph2: reads mf4,5 | bar | 16 MFMA | bar ========
    short8 c00 = RDA(ab, 4, 0), c01 = RDA(ab, 4, 1);
    short8 c10 = RDA(ab, 5, 0), c11 = RDA(ab, 5, 1);
    __builtin_amdgcn_s_barrier();
    asm volatile("s_waitcnt lgkmcnt(0)" ::: "memory");
    __builtin_amdgcn_sched_barrier(0);
    __builtin_amdgcn_s_setprio(1);
    MFMA4(acc[4], c00, bf[0]); MFMA4(acc[4], c01, bf[1]);
    MFMA4(acc[5], c10, bf[0]); MFMA4(acc[5], c11, bf[1]);
    __builtin_amdgcn_s_setprio(0);
    __builtin_amdgcn_s_barrier();

    // ======== ph3: reads mf6,7 | vmcnt(0) (stage landed long ago) | bar | MFMA | bar ====
    short8 d00 = RDA(ab, 6, 0), d01 = RDA(ab, 6, 1);
    short8 d10 = RDA(ab, 7, 0), d11 = RDA(ab, 7, 1);
    asm volatile("s_waitcnt vmcnt(0)" ::: "memory");     // issued 3 phases ago -> ~free
    __builtin_amdgcn_s_barrier();
    asm volatile("s_waitcnt lgkmcnt(0)" ::: "memory");
    __builtin_amdgcn_sched_barrier(0);
    __builtin_amdgcn_s_setprio(1);
    MFMA4(acc[6], d00, bf[0]); MFMA4(acc[6], d01, bf[1]);
    MFMA4(acc[7], d10, bf[0]); MFMA4(acc[7], d11, bf[1]);
    __builtin_amdgcn_s_setprio(0);
    __builtin_amdgcn_s_barrier();
  }
#undef RDA
#undef MFMA4

  // epilogue: bias+relu -> Wt-dot -> col reduce -> wn reduce -> gate -> atomicAdd
  float bev[4], wtv[2][4];
#pragma unroll
  for (int n = 0; n < 4; ++n) bev[n] = be[e * 256 + wn * 64 + n * 16 + row16];
#pragma unroll
  for (int t = 0; t < 2; ++t)
#pragma unroll
    for (int n = 0; n < 4; ++n) wtv[t][n] = Wt[t * 256 + wn * 64 + n * 16 + row16];

#pragma unroll
  for (int mf = 0; mf < 8; ++mf) {
#pragma unroll
    for (int j = 0; j < 4; ++j) {
      float p0 = 0.f, p1 = 0.f;
#pragma unroll
      for (int n = 0; n < 4; ++n) {
        float r = fmaxf(acc[mf][n][j] + bev[n], 0.f);
        p0 = fmaf(r, wtv[0][n], p0);
        p1 = fmaf(r, wtv[1][n], p1);
      }
      p0 += __shfl_xor(p0, 1); p1 += __shfl_xor(p1, 1);
      p0 += __shfl_xor(p0, 2); p1 += __shfl_xor(p1, 2);
      p0 += __shfl_xor(p0, 4); p1 += __shfl_xor(p1, 4);
      p0 += __shfl_xor(p0, 8); p1 += __shfl_xor(p1, 8);
      if (row16 == 0) {
        int rw = wm * 128 + mf * 16 + kgrp * 4 + j;
        red_lds[wn][rw][0] = p0;
        red_lds[wn][rw][1] = p1;
      }
    }
  }
  __syncthreads();

  {
    int row = tid >> 1, t = tid & 1;
    float s = red_lds[0][row][t] + red_lds[1][row][t]
            + red_lds[2][row][t] + red_lds[3][row][t];
    float g = gates_ws[(t * 8 + e) * BS + mt * 256 + row];
    atomicAdd(&acc_ws[t * BS + mt * 256 + row], s * g);
  }
}

__global__ void finalize(const float* __restrict__ acc_ws, const float* __restrict__ bt,
                         float* __restrict__ out) {
  int i = blockIdx.x * 256 + threadIdx.x;   // 65536
  int t = i >> 15;
  float s = fmaxf(acc_ws[i] + bt[t], 0.f);
  out[i] = 1.f / (1.f + __expf(-s));
}

extern "C" void kernel_launch(void* const* d_in, const int* in_sizes, int n_in,
                              void* d_out, int out_size, void* d_ws, size_t ws_size,
                              hipStream_t stream) {
  const float* xv = (const float*)d_in[0];
  const float* We = (const float*)d_in[1];
  const float* be = (const float*)d_in[2];
  const float* Wg = (const float*)d_in[3];
  const float* bg = (const float*)d_in[4];
  const float* Wt = (const float*)d_in[5];
  const float* bt = (const float*)d_in[6];
  float* out = (float*)d_out;

  unsigned char* ws = (unsigned char*)d_ws;
  unsigned short* WeT      = (unsigned short*)(ws);                     // 2 MiB
  unsigned short* WgT      = (unsigned short*)(ws + (2u << 20));        // 16 KiB
  unsigned short* Abf      = (unsigned short*)(ws + (4u << 20));        // 32 MiB
  float*          gates_ws = (float*)(ws + (36u << 20));                // 2 MiB
  float*          acc_ws   = (float*)(ws + (38u << 20));                // 256 KiB

  hipMemsetAsync(acc_ws, 0, 2 * BS * sizeof(float), stream);
  prep_w<<<528, 256, 0, stream>>>(We, Wg, WeT, WgT);
  conv_gates<<<512, 256, 0, stream>>>(xv, WgT, bg, Abf, gates_ws);
  mmoe_main<<<1024, 512, 0, stream>>>(Abf, WeT, gates_ws, be, Wt, acc_ws);
  finalize<<<256, 256, 0, stream>>>(acc_ws, bt, out);
}